// Round 3
// baseline (129.175 us; speedup 1.0000x reference)
//
#include <hip/hip_runtime.h>
#include <hip/hip_bf16.h>

typedef __attribute__((ext_vector_type(8))) short bf16x8;
typedef __attribute__((ext_vector_type(4))) float f32x4;
typedef __attribute__((ext_vector_type(4))) short short4v;
typedef unsigned short ushort_t;

#define BB 128
#define SS 8
#define CC 120
#define LL 469
#define HH 64

constexpr int NBATCH = SS * BB;        // 1024 (s,b) pairs
constexpr int KSTEPS = (LL + 31) / 32; // 15

// ---- LDS layout ----
// phase 1: Xf[120][32] f32 @0 (15360 B, single-buffered),
//          Wl[2][192][40] bf16 @15360 (30720 B) -> 46080 B
// phase 2: Qb @0 (16 KB, [128]x128B swz), Kb @16384, Vb @32768 ([64]x256B swz)
//          Pb @0 (32 KB, [128]x256B swz) aliases Q+K after QK^T barrier
// epilogue: Ob f32 [120][68] @0 (32640 B) after barrier
constexpr int XBUF_FLOATS = 120 * 32;            // 3840
constexpr int XBUF_BYTES  = XBUF_FLOATS * 4;     // 15360
constexpr int WBUF_SHORTS = 192 * 40;            // 7680
constexpr int WBUF_BYTES  = WBUF_SHORTS * 2;     // 15360
constexpr int SMEM_BYTES  = 49152;               // max(46080, 48K)
constexpr int WIMG_BYTES  = KSTEPS * WBUF_BYTES; // 230400

__device__ __forceinline__ ushort_t f2bf(float f) {
  __hip_bfloat16 h = __float2bfloat16(f);
  return __builtin_bit_cast(ushort_t, h);
}

__device__ __forceinline__ void gload_lds4(const void* g, void* l) {
  __builtin_amdgcn_global_load_lds(
      (const __attribute__((address_space(1))) unsigned int*)g,
      (__attribute__((address_space(3))) unsigned int*)l, 4, 0, 0);
}
__device__ __forceinline__ void gload_lds16(const void* g, void* l) {
  __builtin_amdgcn_global_load_lds(
      (const __attribute__((address_space(1))) unsigned int*)g,
      (__attribute__((address_space(3))) unsigned int*)l, 16, 0, 0);
}

// XOR-swizzled LDS address for phase-2 tiles
__device__ __forceinline__ char* sptr(char* base, int row, int stride, int byteoff) {
  return base + row * stride + (byteoff ^ ((row & 7) << 4));
}

__global__ void prep_w(const float* __restrict__ Wk, const float* __restrict__ Wq,
                       const float* __restrict__ Wv, ushort_t* __restrict__ wimg) {
  int idx = blockIdx.x * 256 + threadIdx.x; // 15*192*40 = 115200 exactly
  int t = idx / (192 * 40);
  int rem = idx % (192 * 40);
  int col = rem / 40;
  int kk = rem % 40;
  int k = t * 32 + kk;
  int wsel = col >> 6, h = col & 63;
  const float* wp = (wsel == 0) ? Wk : (wsel == 1) ? Wq : Wv;
  float v = (kk < 32 && k < LL) ? wp[(size_t)k * HH + h] : 0.f;
  wimg[idx] = f2bf(v);
}

template <bool WIMG>
__global__ __launch_bounds__(256, 3)
void fused_regional_head(const float* __restrict__ x,
                         const float* __restrict__ Wk,
                         const float* __restrict__ Wq,
                         const float* __restrict__ Wv,
                         const ushort_t* __restrict__ wimg,
                         float* __restrict__ out) {
  __shared__ char smem[SMEM_BYTES];
  const int tid = threadIdx.x;
  const int lane = tid & 63;
  const int wv = tid >> 6;   // wave 0..3, owns rows 32*wv .. 32*wv+31
  const int lr = lane & 15;
  const int lg = lane >> 4;
  const int batch = blockIdx.x;
  const size_t xbase = (size_t)batch * CC * LL;

  float* Xf = (float*)smem;                              // [120][32] single buffer
  ushort_t* Wl = (ushort_t*)(smem + XBUF_BYTES);         // [2][192][40]

  // X stage (single buffer): rows 0..119, 32 k-words. LDS linear; global source
  // chunk-XOR-swizzled so ds_read_b128 of logical chunk s reads phys s^(row&7).
  auto stage_x = [&](int t) {
    const int k0 = t * 32;
#pragma unroll
    for (int i = 0; i < 15; ++i) {
      int slot = i * 4 + wv;              // 0..59 (wave-uniform)
      int dw = slot * 64 + lane;          // dword in [0,3840)
      int row = dw >> 5;
      int w = dw & 31;
      int s = w >> 2, q = w & 3;
      int lw = ((s ^ (row & 7)) << 2) | q; // logical k-word
      int k = k0 + lw;
      if (k < LL) gload_lds4(x + xbase + (size_t)row * LL + k, Xf + slot * 64);
      else Xf[dw] = 0.f; // tail zero-fill
    }
  };

  auto stage_w = [&](int buf, int t) {
    ushort_t* wb = Wl + buf * WBUF_SHORTS;
    if constexpr (WIMG) {
      const char* src = (const char*)(wimg + t * WBUF_SHORTS);
#pragma unroll
      for (int i = 0; i < 4; ++i) {
        int c = wv + 4 * i; // 1024-byte chunks, 15 total
        if (c < 15) gload_lds16(src + c * 1024 + lane * 16, (char*)wb + c * 1024);
      }
    } else {
      const int k0 = t * 32;
#pragma unroll
      for (int j = 0; j < 24; ++j) {
        int idx = j * 256 + tid;
        int col = idx >> 5, kk = idx & 31;
        int k = k0 + kk;
        int wsel = col >> 6, h = col & 63;
        const float* wp = (wsel == 0) ? Wk : (wsel == 1) ? Wq : Wv;
        float v = (k < LL) ? wp[(size_t)k * HH + h] : 0.f;
        wb[col * 40 + kk] = f2bf(v);
      }
    }
  };

  // ---------------- phase 1: QKV = X @ [Wk|Wq|Wv] ----------------
  f32x4 acc[2][12];
#pragma unroll
  for (int m = 0; m < 2; ++m)
#pragma unroll
    for (int n = 0; n < 12; ++n) acc[m][n] = (f32x4){0.f, 0.f, 0.f, 0.f};

  stage_x(0);
  stage_w(0, 0);
  const int row0 = wv * 32 + lr;        // < 120 always
  const int row1 = wv * 32 + 16 + lr;   // >= 120 for wave3, lr>=8
  const bool r1ok = row1 < CC;
  for (int t = 0; t < KSTEPS; ++t) {
    __syncthreads(); // A: X(t), W(t) staged
    // raw A-frag reads (fp32, swizzled chunks) -- only thing between barriers
    f32x4 z = (f32x4){0.f, 0.f, 0.f, 0.f};
    f32x4 c00 = *(const f32x4*)(Xf + row0 * 32 + ((lg * 2) ^ (row0 & 7)) * 4);
    f32x4 c01 = *(const f32x4*)(Xf + row0 * 32 + ((lg * 2 + 1) ^ (row0 & 7)) * 4);
    f32x4 c10 = r1ok ? *(const f32x4*)(Xf + row1 * 32 + ((lg * 2) ^ (row1 & 7)) * 4) : z;
    f32x4 c11 = r1ok ? *(const f32x4*)(Xf + row1 * 32 + ((lg * 2 + 1) ^ (row1 & 7)) * 4) : z;
    if (t + 1 < KSTEPS) stage_w((t + 1) & 1, t + 1); // other W buffer: safe now
    __syncthreads(); // B: all waves hold A-frags -> X buffer reusable
    if (t + 1 < KSTEPS) stage_x(t + 1);
    bf16x8 a0, a1;
#pragma unroll
    for (int j = 0; j < 4; ++j) {
      a0[j] = (short)f2bf(c00[j]); a0[4 + j] = (short)f2bf(c01[j]);
      a1[j] = (short)f2bf(c10[j]); a1[4 + j] = (short)f2bf(c11[j]);
    }
    const ushort_t* wb = Wl + (t & 1) * WBUF_SHORTS;
#pragma unroll
    for (int n = 0; n < 12; ++n) {
      bf16x8 b = *(const bf16x8*)(wb + (n * 16 + lr) * 40 + lg * 8);
      acc[0][n] = __builtin_amdgcn_mfma_f32_16x16x32_bf16(a0, b, acc[0][n], 0, 0, 0);
      acc[1][n] = __builtin_amdgcn_mfma_f32_16x16x32_bf16(a1, b, acc[1][n], 0, 0, 0);
    }
  }
  __syncthreads(); // staging region dead; phase-2 tiles take over

  // ---------------- write Q,K,V (bf16, swizzled) ----------------
  char* Qb = smem;
  char* Kb = smem + 16384;
  char* Vb = smem + 32768;
  char* Pb = smem;
#pragma unroll
  for (int mt = 0; mt < 2; ++mt) {
#pragma unroll
    for (int r = 0; r < 4; ++r) {
      int row = wv * 32 + mt * 16 + lg * 4 + r;
#pragma unroll
      for (int n = 0; n < 4; ++n) {
        *(ushort_t*)sptr(Kb, row, 128, (n * 16 + lr) * 2) = f2bf(acc[mt][n][r]);
        *(ushort_t*)sptr(Qb, row, 128, (n * 16 + lr) * 2) = f2bf(acc[mt][4 + n][r]);
      }
    }
    // V^T packed: 4 consecutive d-columns -> ds_write_b64
#pragma unroll
    for (int n = 0; n < 4; ++n) {
      short4v pk;
#pragma unroll
      for (int r = 0; r < 4; ++r) pk[r] = (short)f2bf(acc[mt][8 + n][r]);
      *(short4v*)sptr(Vb, n * 16 + lr, 256, (wv * 32 + mt * 16 + lg * 4) * 2) = pk;
    }
  }
  __syncthreads();

  // ---------------- QK^T ----------------
  f32x4 accw[2][8];
#pragma unroll
  for (int m = 0; m < 2; ++m)
#pragma unroll
    for (int n = 0; n < 8; ++n) accw[m][n] = (f32x4){0.f, 0.f, 0.f, 0.f};
#pragma unroll
  for (int ks = 0; ks < 2; ++ks) {
    bf16x8 a0 = *(const bf16x8*)sptr(Qb, wv * 32 + lr, 128, ks * 64 + lg * 16);
    bf16x8 a1 = *(const bf16x8*)sptr(Qb, wv * 32 + 16 + lr, 128, ks * 64 + lg * 16);
#pragma unroll
    for (int n = 0; n < 8; ++n) {
      bf16x8 b = *(const bf16x8*)sptr(Kb, n * 16 + lr, 128, ks * 64 + lg * 16);
      accw[0][n] = __builtin_amdgcn_mfma_f32_16x16x32_bf16(a0, b, accw[0][n], 0, 0, 0);
      accw[1][n] = __builtin_amdgcn_mfma_f32_16x16x32_bf16(a1, b, accw[1][n], 0, 0, 0);
    }
  }
  __syncthreads(); // all done reading Q/K before P overwrites

  // ---------------- softmax (wave-parallel over 16-lane col groups) ----------------
#pragma unroll
  for (int mt = 0; mt < 2; ++mt)
#pragma unroll
    for (int r = 0; r < 4; ++r) {
      float l[8];
      float m = -1e30f;
#pragma unroll
      for (int n = 0; n < 8; ++n) {
        float v = accw[mt][n][r] * 0.125f;
        if (n == 7 && lr >= 8) v = -1e30f; // col = 112+lr >= 120 masked
        l[n] = v;
        m = fmaxf(m, v);
      }
#pragma unroll
      for (int off = 1; off < 16; off <<= 1) m = fmaxf(m, __shfl_xor(m, off));
      float s = 0.f;
#pragma unroll
      for (int n = 0; n < 8; ++n) {
        float p = __expf(l[n] - m);
        l[n] = p;
        s += p;
      }
#pragma unroll
      for (int off = 1; off < 16; off <<= 1) s += __shfl_xor(s, off);
      float inv = 1.f / s;
      int row = wv * 32 + mt * 16 + lg * 4 + r;
#pragma unroll
      for (int n = 0; n < 8; ++n)
        *(ushort_t*)sptr(Pb, row, 256, (n * 16 + lr) * 2) = f2bf(l[n] * inv);
    }
  // no barrier: each wave reads only its own P rows; V covered by barrier above

  // ---------------- out = P @ V ----------------
  f32x4 acco[2][4];
#pragma unroll
  for (int m = 0; m < 2; ++m)
#pragma unroll
    for (int n = 0; n < 4; ++n) acco[m][n] = (f32x4){0.f, 0.f, 0.f, 0.f};
#pragma unroll
  for (int ks = 0; ks < 4; ++ks) {
    bf16x8 a0 = *(const bf16x8*)sptr(Pb, wv * 32 + lr, 256, ks * 64 + lg * 16);
    bf16x8 a1 = *(const bf16x8*)sptr(Pb, wv * 32 + 16 + lr, 256, ks * 64 + lg * 16);
#pragma unroll
    for (int n = 0; n < 4; ++n) {
      bf16x8 b = *(const bf16x8*)sptr(Vb, n * 16 + lr, 256, ks * 64 + lg * 16);
      acco[0][n] = __builtin_amdgcn_mfma_f32_16x16x32_bf16(a0, b, acco[0][n], 0, 0, 0);
      acco[1][n] = __builtin_amdgcn_mfma_f32_16x16x32_bf16(a1, b, acco[1][n], 0, 0, 0);
    }
  }

  // ---------------- epilogue: LDS transpose -> float4 coalesced stores ----------------
  __syncthreads(); // P/V dead
  float* Ob = (float*)smem; // [120][68] f32
#pragma unroll
  for (int mt = 0; mt < 2; ++mt)
#pragma unroll
    for (int r = 0; r < 4; ++r) {
      int row = wv * 32 + mt * 16 + lg * 4 + r;
      if (row < CC) {
#pragma unroll
        for (int n = 0; n < 4; ++n)
          Ob[row * 68 + n * 16 + lr] = acco[mt][n][r];
      }
    }
  __syncthreads();
  const size_t obase = (size_t)batch * CC * HH;
#pragma unroll
  for (int i = 0; i < 8; ++i) {
    int idx = i * 256 + tid; // float4 index, 1920 total
    if (idx < 1920) {
      int row = idx >> 4;
      int c4 = (idx & 15) * 4;
      f32x4 v = *(const f32x4*)(Ob + row * 68 + c4);
      *(f32x4*)(out + obase + (size_t)idx * 4) = v;
    }
  }
}

extern "C" void kernel_launch(void* const* d_in, const int* in_sizes, int n_in,
                              void* d_out, int out_size, void* d_ws, size_t ws_size,
                              hipStream_t stream) {
  (void)in_sizes; (void)n_in; (void)out_size;
  const float* x  = (const float*)d_in[0];
  const float* Wk = (const float*)d_in[1];
  const float* Wq = (const float*)d_in[2];
  const float* Wv = (const float*)d_in[3];
  float* out = (float*)d_out;
  if (ws_size >= (size_t)WIMG_BYTES && d_ws != nullptr) {
    ushort_t* wimg = (ushort_t*)d_ws;
    prep_w<<<450, 256, 0, stream>>>(Wk, Wq, Wv, wimg);
    fused_regional_head<true><<<NBATCH, 256, 0, stream>>>(x, Wk, Wq, Wv, wimg, out);
  } else {
    fused_regional_head<false><<<NBATCH, 256, 0, stream>>>(x, Wk, Wq, Wv, nullptr, out);
  }
}

// Round 4
// 81.325 us; speedup vs baseline: 1.5884x; 1.5884x over previous
//
#include <hip/hip_runtime.h>
#include <hip/hip_bf16.h>

typedef __attribute__((ext_vector_type(8))) short bf16x8;
typedef __attribute__((ext_vector_type(4))) float f32x4;
typedef __attribute__((ext_vector_type(4))) short short4v;
typedef unsigned short ushort_t;

#define CC 120
#define LL 469
#define HH 64

constexpr int NBATCH = 1024;           // (s,b) pairs; raw reshape => batch index contiguous
constexpr int KSTEPS = (LL + 31) / 32; // 15

// ---- LDS layout ----
// phase 1: Xb[2][120][40] bf16 @0 (19200 B), Wl[2][192][40] bf16 @19200 (30720 B) -> 49920 B
// phase 2: Qb @0 (16 KB, [128]x128B swz), Kb @16384, Vb @32768 ([64]x256B swz)
//          Pb @0 (32 KB, [128]x256B swz) aliases Q+K after QK^T barrier
// epilogue: Ob f32 [120][68] @0 (32640 B)
constexpr int XB_STRIDE   = 40;                  // shorts; 80 B row stride (16B-aligned, 2-way banks)
constexpr int XBUF_SHORTS = CC * XB_STRIDE;      // 4800
constexpr int WBUF_SHORTS = 192 * 40;            // 7680
constexpr int WBUF_BYTES  = WBUF_SHORTS * 2;     // 15360
constexpr int SMEM_BYTES  = 2 * XBUF_SHORTS * 2 + 2 * WBUF_BYTES; // 49920 (>= phase2's 48K)
constexpr int WIMG_BYTES  = KSTEPS * WBUF_BYTES; // 230400

__device__ __forceinline__ ushort_t f2bf(float f) {
  __hip_bfloat16 h = __float2bfloat16(f);
  return __builtin_bit_cast(ushort_t, h);
}

__device__ __forceinline__ void gload_lds16(const void* g, void* l) {
  __builtin_amdgcn_global_load_lds(
      (const __attribute__((address_space(1))) unsigned int*)g,
      (__attribute__((address_space(3))) unsigned int*)l, 16, 0, 0);
}

// XOR-swizzled LDS address for phase-2 tiles
__device__ __forceinline__ char* sptr(char* base, int row, int stride, int byteoff) {
  return base + row * stride + (byteoff ^ ((row & 7) << 4));
}

__global__ void prep_w(const float* __restrict__ Wk, const float* __restrict__ Wq,
                       const float* __restrict__ Wv, ushort_t* __restrict__ wimg) {
  int idx = blockIdx.x * 256 + threadIdx.x; // 15*192*40 = 115200 exactly
  int t = idx / (192 * 40);
  int rem = idx % (192 * 40);
  int col = rem / 40;
  int kk = rem % 40;
  int k = t * 32 + kk;
  int wsel = col >> 6, h = col & 63;
  const float* wp = (wsel == 0) ? Wk : (wsel == 1) ? Wq : Wv;
  float v = (kk < 32 && k < LL) ? wp[(size_t)k * HH + h] : 0.f;
  wimg[idx] = f2bf(v);
}

template <bool WIMG>
__global__ __launch_bounds__(256, 3)
void fused_regional_head(const float* __restrict__ x,
                         const float* __restrict__ Wk,
                         const float* __restrict__ Wq,
                         const float* __restrict__ Wv,
                         const ushort_t* __restrict__ wimg,
                         float* __restrict__ out) {
  __shared__ char smem[SMEM_BYTES];
  const int tid = threadIdx.x;
  const int lane = tid & 63;
  const int wv = tid >> 6;   // wave 0..3, owns rows 32*wv .. 32*wv+31
  const int lr = lane & 15;
  const int lg = lane >> 4;
  const int batch = blockIdx.x;
  const size_t xbase = (size_t)batch * CC * LL;

  ushort_t* Xb = (ushort_t*)smem;                        // [2][120][40] bf16
  ushort_t* Wl = (ushort_t*)(smem + 2 * XBUF_SHORTS * 2);// [2][192][40] bf16

  // staging decomposition (all 256 threads): thread covers k-col (tid&31) of
  // rows (tid>>5) + 8*i, i=0..14  -> loads coalesced (32 lanes = 32 consecutive k)
  const int skk = tid & 31;
  const int sr0 = tid >> 5;

  // T14 part 1: issue 15 scalar global loads (coalesced 128B/row per half-wave)
  auto xload = [&](int t, float* v) {
    const int k = t * 32 + skk;
    const bool kok = k < LL;
#pragma unroll
    for (int i = 0; i < 15; ++i) {
      v[i] = 0.f;
      if (kok) v[i] = x[xbase + (size_t)(i * 8 + sr0) * LL + k];
    }
  };
  // T14 part 2: convert + LDS write (step end, other buffer)
  auto xwrite = [&](int buf, const float* v) {
    ushort_t* xb = Xb + buf * XBUF_SHORTS;
#pragma unroll
    for (int i = 0; i < 15; ++i)
      xb[(i * 8 + sr0) * XB_STRIDE + skk] = f2bf(v[i]);
  };

  auto stage_w = [&](int buf, int t) {
    ushort_t* wb = Wl + buf * WBUF_SHORTS;
    if constexpr (WIMG) {
      const char* src = (const char*)(wimg + t * WBUF_SHORTS);
#pragma unroll
      for (int i = 0; i < 4; ++i) {
        int c = wv + 4 * i; // 1024-byte chunks, 15 total
        if (c < 15) gload_lds16(src + c * 1024 + lane * 16, (char*)wb + c * 1024);
      }
    } else {
      const int k0 = t * 32;
#pragma unroll
      for (int j = 0; j < 24; ++j) {
        int idx = j * 256 + tid;
        int col = idx >> 5, kk = idx & 31;
        int k = k0 + kk;
        int wsel = col >> 6, h = col & 63;
        const float* wp = (wsel == 0) ? Wk : (wsel == 1) ? Wq : Wv;
        float v = (k < LL) ? wp[(size_t)k * HH + h] : 0.f;
        wb[col * 40 + kk] = f2bf(v);
      }
    }
  };

  // ---------------- phase 1: QKV = X @ [Wk|Wq|Wv] ----------------
  f32x4 acc[2][12];
#pragma unroll
  for (int m = 0; m < 2; ++m)
#pragma unroll
    for (int n = 0; n < 12; ++n) acc[m][n] = (f32x4){0.f, 0.f, 0.f, 0.f};

  {
    float v0[15];
    xload(0, v0);
    xwrite(0, v0);
  }
  stage_w(0, 0);

  const int row0 = wv * 32 + lr;      // < 120 always
  const int row1 = wv * 32 + 16 + lr; // >= 120 for wave3, lr>=8
  const bool r1ok = row1 < CC;

  float vx[15];
  for (int t = 0; t < KSTEPS; ++t) {
    __syncthreads(); // X(t), W(t) staged & visible (barrier drains vmcnt)
    // issue next-tile loads first (longest latency, full step of cover)
    if (t + 1 < KSTEPS) {
      xload(t + 1, vx);
      stage_w((t + 1) & 1, t + 1);
    }
    const ushort_t* xb = Xb + (t & 1) * XBUF_SHORTS;
    const ushort_t* wb = Wl + (t & 1) * WBUF_SHORTS;
    bf16x8 a0 = *(const bf16x8*)(xb + row0 * XB_STRIDE + lg * 8);
    bf16x8 a1;
    if (r1ok) a1 = *(const bf16x8*)(xb + row1 * XB_STRIDE + lg * 8);
    else { bf16x8 z = {0,0,0,0,0,0,0,0}; a1 = z; }
#pragma unroll
    for (int n = 0; n < 12; ++n) {
      bf16x8 b = *(const bf16x8*)(wb + (n * 16 + lr) * 40 + lg * 8);
      acc[0][n] = __builtin_amdgcn_mfma_f32_16x16x32_bf16(a0, b, acc[0][n], 0, 0, 0);
      acc[1][n] = __builtin_amdgcn_mfma_f32_16x16x32_bf16(a1, b, acc[1][n], 0, 0, 0);
    }
    if (t + 1 < KSTEPS) xwrite((t + 1) & 1, vx); // write-late into other buffer
  }
  __syncthreads(); // staging region dead; phase-2 tiles take over

  // ---------------- write Q,K,V (bf16, swizzled) ----------------
  char* Qb = smem;
  char* Kb = smem + 16384;
  char* Vb = smem + 32768;
  char* Pb = smem;
#pragma unroll
  for (int mt = 0; mt < 2; ++mt) {
#pragma unroll
    for (int r = 0; r < 4; ++r) {
      int row = wv * 32 + mt * 16 + lg * 4 + r;
#pragma unroll
      for (int n = 0; n < 4; ++n) {
        *(ushort_t*)sptr(Kb, row, 128, (n * 16 + lr) * 2) = f2bf(acc[mt][n][r]);
        *(ushort_t*)sptr(Qb, row, 128, (n * 16 + lr) * 2) = f2bf(acc[mt][4 + n][r]);
      }
    }
    // V^T packed: 4 consecutive d-rows -> ds_write_b64
#pragma unroll
    for (int n = 0; n < 4; ++n) {
      short4v pk;
#pragma unroll
      for (int r = 0; r < 4; ++r) pk[r] = (short)f2bf(acc[mt][8 + n][r]);
      *(short4v*)sptr(Vb, n * 16 + lr, 256, (wv * 32 + mt * 16 + lg * 4) * 2) = pk;
    }
  }
  __syncthreads();

  // ---------------- QK^T ----------------
  f32x4 accw[2][8];
#pragma unroll
  for (int m = 0; m < 2; ++m)
#pragma unroll
    for (int n = 0; n < 8; ++n) accw[m][n] = (f32x4){0.f, 0.f, 0.f, 0.f};
#pragma unroll
  for (int ks = 0; ks < 2; ++ks) {
    bf16x8 a0 = *(const bf16x8*)sptr(Qb, wv * 32 + lr, 128, ks * 64 + lg * 16);
    bf16x8 a1 = *(const bf16x8*)sptr(Qb, wv * 32 + 16 + lr, 128, ks * 64 + lg * 16);
#pragma unroll
    for (int n = 0; n < 8; ++n) {
      bf16x8 b = *(const bf16x8*)sptr(Kb, n * 16 + lr, 128, ks * 64 + lg * 16);
      accw[0][n] = __builtin_amdgcn_mfma_f32_16x16x32_bf16(a0, b, accw[0][n], 0, 0, 0);
      accw[1][n] = __builtin_amdgcn_mfma_f32_16x16x32_bf16(a1, b, accw[1][n], 0, 0, 0);
    }
  }
  __syncthreads(); // all done reading Q/K before P overwrites

  // ---------------- softmax (wave-parallel over 16-lane col groups) ----------------
#pragma unroll
  for (int mt = 0; mt < 2; ++mt)
#pragma unroll
    for (int r = 0; r < 4; ++r) {
      float l[8];
      float m = -1e30f;
#pragma unroll
      for (int n = 0; n < 8; ++n) {
        float v = accw[mt][n][r] * 0.125f;
        if (n == 7 && lr >= 8) v = -1e30f; // col = 112+lr >= 120 masked
        l[n] = v;
        m = fmaxf(m, v);
      }
#pragma unroll
      for (int off = 1; off < 16; off <<= 1) m = fmaxf(m, __shfl_xor(m, off));
      float s = 0.f;
#pragma unroll
      for (int n = 0; n < 8; ++n) {
        float p = __expf(l[n] - m);
        l[n] = p;
        s += p;
      }
#pragma unroll
      for (int off = 1; off < 16; off <<= 1) s += __shfl_xor(s, off);
      float inv = 1.f / s;
      int row = wv * 32 + mt * 16 + lg * 4 + r;
#pragma unroll
      for (int n = 0; n < 8; ++n)
        *(ushort_t*)sptr(Pb, row, 256, (n * 16 + lr) * 2) = f2bf(l[n] * inv);
    }
  // no barrier: each wave reads only its own P rows; V covered by barrier above

  // ---------------- out = P @ V ----------------
  f32x4 acco[2][4];
#pragma unroll
  for (int m = 0; m < 2; ++m)
#pragma unroll
    for (int n = 0; n < 4; ++n) acco[m][n] = (f32x4){0.f, 0.f, 0.f, 0.f};
#pragma unroll
  for (int ks = 0; ks < 4; ++ks) {
    bf16x8 a0 = *(const bf16x8*)sptr(Pb, wv * 32 + lr, 256, ks * 64 + lg * 16);
    bf16x8 a1 = *(const bf16x8*)sptr(Pb, wv * 32 + 16 + lr, 256, ks * 64 + lg * 16);
#pragma unroll
    for (int n = 0; n < 4; ++n) {
      bf16x8 b = *(const bf16x8*)sptr(Vb, n * 16 + lr, 256, ks * 64 + lg * 16);
      acco[0][n] = __builtin_amdgcn_mfma_f32_16x16x32_bf16(a0, b, acco[0][n], 0, 0, 0);
      acco[1][n] = __builtin_amdgcn_mfma_f32_16x16x32_bf16(a1, b, acco[1][n], 0, 0, 0);
    }
  }

  // ---------------- epilogue: LDS transpose -> float4 coalesced stores ----------------
  __syncthreads(); // P/V dead
  float* Ob = (float*)smem; // [120][68] f32
#pragma unroll
  for (int mt = 0; mt < 2; ++mt)
#pragma unroll
    for (int r = 0; r < 4; ++r) {
      int row = wv * 32 + mt * 16 + lg * 4 + r;
      if (row < CC) {
#pragma unroll
        for (int n = 0; n < 4; ++n)
          Ob[row * 68 + n * 16 + lr] = acco[mt][n][r];
      }
    }
  __syncthreads();
  const size_t obase = (size_t)batch * CC * HH;
#pragma unroll
  for (int i = 0; i < 8; ++i) {
    int idx = i * 256 + tid; // float4 index, 1920 total
    if (idx < 1920) {
      int row = idx >> 4;
      int c4 = (idx & 15) * 4;
      f32x4 v = *(const f32x4*)(Ob + row * 68 + c4);
      *(f32x4*)(out + obase + (size_t)idx * 4) = v;
    }
  }
}

extern "C" void kernel_launch(void* const* d_in, const int* in_sizes, int n_in,
                              void* d_out, int out_size, void* d_ws, size_t ws_size,
                              hipStream_t stream) {
  (void)in_sizes; (void)n_in; (void)out_size;
  const float* x  = (const float*)d_in[0];
  const float* Wk = (const float*)d_in[1];
  const float* Wq = (const float*)d_in[2];
  const float* Wv = (const float*)d_in[3];
  float* out = (float*)d_out;
  if (ws_size >= (size_t)WIMG_BYTES && d_ws != nullptr) {
    ushort_t* wimg = (ushort_t*)d_ws;
    prep_w<<<450, 256, 0, stream>>>(Wk, Wq, Wv, wimg);
    fused_regional_head<true><<<NBATCH, 256, 0, stream>>>(x, Wk, Wq, Wv, wimg, out);
  } else {
    fused_regional_head<false><<<NBATCH, 256, 0, stream>>>(x, Wk, Wq, Wv, nullptr, out);
  }
}